// Round 8
// baseline (174.706 us; speedup 1.0000x reference)
//
#include <hip/hip_runtime.h>
#include <math.h>

// Problem constants (B=16, C=3 -> 48 planes of 512x512)
#define H_IMG 512
#define W_IMG 512
#define TW 32              // strip width (output cols per block)
#define CH 32              // output rows per chunk
#define NCHUNK 4           // chunks per block -> 128 output rows per block
#define STRIP (CH*NCHUNK)  // 128
#define HALO 5
#define WS11 11
#define RING 42            // ring rows: live window is 42 (32 new + 10 reused)
#define RS 36              // row stride in floats (32 cols + pad, 16B-aligned rows)
#define FSTR (RING*RS)     // 1512 floats per field
#define NF 4               // fields: s, d, s^2, d^2  (s=x+y, d=x-y)
#define NTHREADS 256

typedef float f2 __attribute__((ext_vector_type(2)));

// Gaussian 11-tap, sigma=1.5, normalized; folds to literals after unroll.
// Out-of-range taps -> 0 so packed pairs can run harmlessly.
__host__ __device__ constexpr float WT(int t) {
    return (t==0||t==10) ? 0.00102838f :
           (t==1||t==9)  ? 0.00759873f :
           (t==2||t==8)  ? 0.03600075f :
           (t==3||t==7)  ? 0.10936070f :
           (t==4||t==6)  ? 0.21300556f :
           (t==5)        ? 0.26601172f : 0.0f;
}

static __device__ __forceinline__ f2 splat2(float v) { f2 r = {v, v}; return r; }

// Column-strip kernel: block = 32 cols x 128 rows of one plane.
// (s,d) transform: SSIM needs only {2mxmy, mx^2+my^2, 2sxy, sxx+syy},
// all derivable from conv(s), conv(d), conv(s^2), conv(d^2) with
// s=x+y, d=x-y  (s^2-d^2=4xy, s^2+d^2=2(x^2+y^2)).  4 fields instead
// of 5: -20% conv FMAs, -20% Stage-B LDS reads, LDS 30.2->24.2 KB
// (6 blocks/CU).  MSE = mean(d^2) reuses the d^2 field.
// Stage A: 256 tasks/chunk = 1/thread (chunk 0: 336).
// Stage B: 256 tasks/chunk = 1/thread (4 rows x 1 col, row-pair packed
//          f2 accums, scalar b32 LDS reads -> bank-conflict-free).
__global__ __launch_bounds__(NTHREADS, 6) void ssim_mse_tile(
        const float* __restrict__ cover, const float* __restrict__ wmed,
        float* __restrict__ part, int nParts) {
    __shared__ __align__(16) float rbuf[NF*FSTR];   // 24192 B -> 6 blocks/CU

    const int tid = threadIdx.x;
    const int bx  = blockIdx.x & 15;          // x-strip
    const int ys  = (blockIdx.x >> 4) & 3;    // y quarter
    const int pl  = blockIdx.x >> 6;          // plane
    const size_t pbase = (size_t)pl * (H_IMG*W_IMG);
    const float* xp = wmed + pbase;           // x = wmed, y = cover
    const float* yp = cover + pbase;
    const int Y0  = ys << 7;                  // 0,128,256,384
    const int tx0 = bx*TW - HALO;
    const bool xin = (bx != 0) && (bx != 15); // fast-path columns

    float ssim_acc = 0.f, mse_acc = 0.f;

    for (int k = 0; k < NCHUNK; ++k) {
        // ---- Stage A: hconv the NEW rows of this chunk into the ring ----
        // chunk 0: hr in [-5, 37) (42 rows); chunk k>0: hr in [32k+5, 32k+37)
        const int nrows = (k == 0) ? (CH + 2*HALO) : CH;
        const int hr0   = (k == 0) ? -HALO : (CH*k + HALO);
        const int ntask = nrows << 3;          // 8 col-groups of 4

        for (int t = tid; t < ntask; t += NTHREADS) {
            const int r  = t >> 3, c0 = (t & 7) << 2;
            const int hr = hr0 + r;                  // strip-relative row
            const int gy = Y0 + hr;                  // global row
            const int slot = (hr + HALO) % RING;     // ring slot (>=0)
            const bool rok = (unsigned)gy < (unsigned)H_IMG;
            float xv[14], yv[14];
            if (rok && xin) {
                // ga = bx*32 + c0 - 8 : 16B-aligned, in [24, 484]
                const int ga = tx0 + c0 - 3;
                const float* rx = xp + (size_t)gy*W_IMG + ga;
                const float* ry = yp + (size_t)gy*W_IMG + ga;
                float4 XA = *(const float4*)(rx);
                float4 XB = *(const float4*)(rx + 4);
                float4 XC = *(const float4*)(rx + 8);
                float4 XD = *(const float4*)(rx + 12);
                float  XE = rx[16];
                float4 YA = *(const float4*)(ry);
                float4 YB = *(const float4*)(ry + 4);
                float4 YC = *(const float4*)(ry + 8);
                float4 YD = *(const float4*)(ry + 12);
                float  YE = ry[16];
                xv[0]=XA.w;  xv[1]=XB.x;  xv[2]=XB.y;  xv[3]=XB.z;  xv[4]=XB.w;
                xv[5]=XC.x;  xv[6]=XC.y;  xv[7]=XC.z;  xv[8]=XC.w;  xv[9]=XD.x;
                xv[10]=XD.y; xv[11]=XD.z; xv[12]=XD.w; xv[13]=XE;
                yv[0]=YA.w;  yv[1]=YB.x;  yv[2]=YB.y;  yv[3]=YB.z;  yv[4]=YB.w;
                yv[5]=YC.x;  yv[6]=YC.y;  yv[7]=YC.z;  yv[8]=YC.w;  yv[9]=YD.x;
                yv[10]=YD.y; yv[11]=YD.z; yv[12]=YD.w; yv[13]=YE;
            } else if (rok) {
                const int gc = tx0 + c0;
                const float* prx = xp + (size_t)gy*W_IMG + gc;
                const float* pry = yp + (size_t)gy*W_IMG + gc;
#pragma unroll
                for (int j = 0; j < 14; ++j) {
                    bool ok = (unsigned)(gc + j) < (unsigned)W_IMG;
                    xv[j] = ok ? prx[j] : 0.f;
                    yv[j] = ok ? pry[j] : 0.f;
                }
            } else {
#pragma unroll
                for (int j = 0; j < 14; ++j) { xv[j] = 0.f; yv[j] = 0.f; }
            }

            const bool own = (unsigned)hr < (unsigned)STRIP;

            // Packed hconv of {s, d, s^2, d^2}: output-col pairs in f2.
            // MSE fused: d^2 at window cols j=5..8 on owned rows.
            f2 A[NF][2];
#pragma unroll
            for (int f = 0; f < NF; ++f) { A[f][0] = splat2(0.f); A[f][1] = splat2(0.f); }
#pragma unroll
            for (int j = 0; j < 14; ++j) {
                float sj = xv[j] + yv[j];
                float dj = xv[j] - yv[j];
                float s2 = sj*sj, d2 = dj*dj;
                if (j >= 5 && j < 9) {
                    if (own) mse_acc += d2;
                }
#pragma unroll
                for (int p = 0; p < 2; ++p) {
                    const int t0 = j - 2*p;          // tap for m=2p; m=2p+1 uses t0-1
                    if (t0 >= 0 && t0 <= WS11) {
                        const f2 wp = {WT(t0), WT(t0-1)};
                        A[0][p] = __builtin_elementwise_fma(wp, splat2(sj), A[0][p]);
                        A[1][p] = __builtin_elementwise_fma(wp, splat2(dj), A[1][p]);
                        A[2][p] = __builtin_elementwise_fma(wp, splat2(s2), A[2][p]);
                        A[3][p] = __builtin_elementwise_fma(wp, splat2(d2), A[3][p]);
                    }
                }
            }
            float* wb = &rbuf[slot*RS + c0];
#pragma unroll
            for (int f = 0; f < NF; ++f) {
                *(float4*)(wb + f*FSTR) =
                    make_float4(A[f][0].x, A[f][0].y, A[f][1].x, A[f][1].y);
            }
        }
        __syncthreads();

        // ---- Stage B: vertical 11-tap + SSIM; ALL 256 threads.
        //      Task = 4 output rows x 1 col; row-pair packed f2 accums,
        //      b32 LDS reads (bank-conflict-free, measured 0). ----
        {
            const int c  = tid & 31;             // column
            const int rg = tid >> 5;             // row group 0..7
            const int sb = (CH*k + (rg << 2)) % RING;  // slot of row y0-5
            f2 acc[NF][2];
#pragma unroll
            for (int f = 0; f < NF; ++f) {
                acc[f][0] = splat2(0.f); acc[f][1] = splat2(0.f);
            }
            const float* bp = rbuf + c;
#pragma unroll
            for (int i = 0; i < 14; ++i) {
                int sl = sb + i; if (sl >= RING) sl -= RING;
                const float* rp = bp + sl*RS;
#pragma unroll
                for (int f = 0; f < NF; ++f) {
                    float v = rp[f*FSTR];
#pragma unroll
                    for (int p = 0; p < 2; ++p) {
                        const int t0 = i - 2*p;      // tap for row 2p; 2p+1 uses t0-1
                        if (t0 >= 0 && t0 <= WS11) {
                            const f2 wp = {WT(t0), WT(t0-1)};
                            acc[f][p] = __builtin_elementwise_fma(wp, splat2(v), acc[f][p]);
                        }
                    }
                }
            }
            const f2 c1v = {1e-4f, 1e-4f};
            const f2 c2v = {9e-4f, 9e-4f};
            const f2 half = {0.5f, 0.5f};
#pragma unroll
            for (int p = 0; p < 2; ++p) {
                f2 S = acc[0][p], D = acc[1][p];
                f2 Cs = acc[2][p], Cd = acc[3][p];
                f2 SS = S*S, DD = D*D;
                f2 mxmy2 = (SS - DD) * half;         // 2*mx*my
                f2 msq   = (SS + DD) * half;         // mx^2+my^2
                f2 sxy2  = (Cs - Cd) * half - mxmy2; // 2*sxy
                f2 ssum  = (Cs + Cd) * half - msq;   // sxx+syy
                f2 num = (mxmy2 + c1v) * (sxy2 + c2v);
                f2 den = (msq + c1v) * (ssum + c2v);
                ssim_acc += __fdividef(num.x, den.x) + __fdividef(num.y, den.y);
            }
        }
        __syncthreads();   // ring rows reused by next chunk
    }

    // ---- Block reduce (4 waves of 64); reuse rbuf as scratch ----
#pragma unroll
    for (int off = 32; off > 0; off >>= 1) {
        ssim_acc += __shfl_down(ssim_acc, off);
        mse_acc  += __shfl_down(mse_acc, off);
    }
    const int wid = tid >> 6, lane = tid & 63;
    if (lane == 0) { rbuf[wid] = ssim_acc; rbuf[4+wid] = mse_acc; }
    __syncthreads();
    if (tid == 0) {
        part[blockIdx.x] = rbuf[0]+rbuf[1]+rbuf[2]+rbuf[3];
        part[nParts + blockIdx.x] = rbuf[4]+rbuf[5]+rbuf[6]+rbuf[7];
    }
}

// 1024-thread finalize: vectorized partial reduce (double), fast-log BCE,
// curriculum weights.
#define FT 1024
__global__ __launch_bounds__(FT) void finalize_k(
        const float* __restrict__ part, int nParts,
        const float* __restrict__ wm_orig, const float* __restrict__ wm_ext,
        int nWm, const int* __restrict__ epoch_p,
        float* __restrict__ out, double inv_npix, double inv_nwm) {
    __shared__ double red[48];
    int tid = threadIdx.x;
    double s_ssim = 0.0, s_mse = 0.0, s_wl = 0.0;
    const float4* s4 = (const float4*)part;
    const float4* m4 = (const float4*)(part + nParts);
    int n4 = nParts >> 2;
    for (int i = tid; i < n4; i += FT) {
        float4 v = s4[i];
        s_ssim += (double)((v.x + v.y) + (v.z + v.w));
        float4 u = m4[i];
        s_mse  += (double)((u.x + u.y) + (u.z + u.w));
    }
    const float4* p4 = (const float4*)wm_orig;
    const float4* q4 = (const float4*)wm_ext;
    int w4 = nWm >> 2;
    for (int i = tid; i < w4; i += FT) {
        float4 p = p4[i], q = q4[i];
        float a;
        a  = -(p.x*__logf(q.x) + (1.f-p.x)*__logf(1.f-q.x));
        a += -(p.y*__logf(q.y) + (1.f-p.y)*__logf(1.f-q.y));
        a += -(p.z*__logf(q.z) + (1.f-p.z)*__logf(1.f-q.z));
        a += -(p.w*__logf(q.w) + (1.f-p.w)*__logf(1.f-q.w));
        s_wl += (double)a;
    }
#pragma unroll
    for (int off = 32; off > 0; off >>= 1) {
        s_ssim += __shfl_down(s_ssim, off);
        s_mse  += __shfl_down(s_mse, off);
        s_wl   += __shfl_down(s_wl, off);
    }
    int wid = tid >> 6, lane = tid & 63;
    if (lane == 0) { red[wid] = s_ssim; red[16+wid] = s_mse; red[32+wid] = s_wl; }
    __syncthreads();
    if (tid == 0) {
        double ssim_sum = 0.0, mse_sum = 0.0, wl_sum = 0.0;
        for (int i = 0; i < 16; ++i) {
            ssim_sum += red[i]; mse_sum += red[16+i]; wl_sum += red[32+i];
        }
        float sv = (float)(ssim_sum * inv_npix);
        float ml = (float)(mse_sum  * inv_npix);
        float wl = (float)(wl_sum   * inv_nwm);
        int e = *epoch_p;
        float w_img, w_ssim;
        if (e <= 12) {
            w_img = 0.05f; w_ssim = 0.05f;
        } else {
            float progress = fminf(1.0f, (float)(e - 12) / 10.0f);
            w_img  = 0.05f + (0.5f - 0.05f)*progress;
            w_ssim = 0.05f + (0.8f - 0.05f)*progress;
        }
        float sl = 1.0f - sv;
        float total = w_img*ml + w_ssim*sl + 3.0f*wl;
        out[0] = total;
        out[1] = ml;
        out[2] = sv;
        out[3] = wl;
    }
}

extern "C" void kernel_launch(void* const* d_in, const int* in_sizes, int n_in,
                              void* d_out, int out_size, void* d_ws, size_t ws_size,
                              hipStream_t stream) {
    const float* cover   = (const float*)d_in[0];
    const float* wmed    = (const float*)d_in[1];
    const float* wm_orig = (const float*)d_in[2];
    const float* wm_ext  = (const float*)d_in[3];
    const int*   epoch   = (const int*)d_in[4];
    float* out = (float*)d_out;

    int npix   = in_sizes[0];                 // 12,582,912
    int planes = npix / (H_IMG * W_IMG);      // 48
    int nWm    = in_sizes[2];                 // 16,384

    int nBlocks = 16 * 4 * planes;            // 3072 column-strip blocks
    int nParts  = nBlocks;
    float* part = (float*)d_ws;               // 2 * nParts floats (24 KB)

    ssim_mse_tile<<<nBlocks, NTHREADS, 0, stream>>>(cover, wmed, part, nParts);
    finalize_k<<<1, FT, 0, stream>>>(part, nParts, wm_orig, wm_ext, nWm,
                                     epoch, out,
                                     1.0 / (double)npix, 1.0 / (double)nWm);
}

// Round 11
// 174.560 us; speedup vs baseline: 1.0008x; 1.0008x over previous
//
#include <hip/hip_runtime.h>
#include <math.h>

// Problem constants (B=16, C=3 -> 48 planes of 512x512)
#define H_IMG 512
#define W_IMG 512
#define TW 32              // strip width (output cols per block)
#define CH 64              // output rows per chunk
#define NCHUNK 4           // chunks per block -> 256 output rows per block
#define STRIP (CH*NCHUNK)  // 256
#define HALO 5
#define WS11 11
#define RING 74            // ring rows: live window is 74 (64 new + 10 reused)
#define RS 36              // row stride in floats (32 cols + pad, 16B-aligned rows)
#define FSTR (RING*RS)     // 2664 floats per field
#define NF 4               // fields: s, d, s^2, d^2  (s=x+y, d=x-y)
#define NTHREADS 512       // 8 waves

typedef float f2 __attribute__((ext_vector_type(2)));

// Gaussian 11-tap, sigma=1.5, normalized; folds to literals after unroll.
// Out-of-range taps -> 0 so packed pairs can run harmlessly.
__host__ __device__ constexpr float WT(int t) {
    return (t==0||t==10) ? 0.00102838f :
           (t==1||t==9)  ? 0.00759873f :
           (t==2||t==8)  ? 0.03600075f :
           (t==3||t==7)  ? 0.10936070f :
           (t==4||t==6)  ? 0.21300556f :
           (t==5)        ? 0.26601172f : 0.0f;
}

static __device__ __forceinline__ f2 splat2(float v) { f2 r = {v, v}; return r; }

// Column-strip kernel: block = 32 cols x 256 rows of one plane, 512 thr.
// (s,d) transform (R8): 4 conv fields {s,d,s^2,d^2} instead of 5.
// CH=64 chunks (enabled by NF=4's LDS cut): HALF the barrier/latency
// events of CH=32 at the same 75% static occupancy (3 blk x 8 waves;
// LDS-limited, so launch_bounds only needs a loose floor).
// Stage A: 512 tasks/chunk = 1/thread (chunk 0: 592 = 1.16/thr).
// Stage B: 512 tasks/chunk = 1/thread (4 rows x 1 col, row-pair packed
//          f2 accums, scalar b32 LDS reads -> bank-conflict-free).
// Edge x-strips (bx 0,15): ga is 4-aligned so every float4 of a task is
// fully in-range or fully OOB -> same 5-load shape, per-float4 predication.
__global__ __launch_bounds__(NTHREADS, 4) void ssim_mse_tile(
        const float* __restrict__ cover, const float* __restrict__ wmed,
        float* __restrict__ part, int nParts) {
    __shared__ __align__(16) float rbuf[NF*FSTR];   // 42624 B -> 3 blocks/CU

    const int tid = threadIdx.x;
    const int bx  = blockIdx.x & 15;          // x-strip
    const int ys  = (blockIdx.x >> 4) & 1;    // y half
    const int pl  = blockIdx.x >> 5;          // plane
    const size_t pbase = (size_t)pl * (H_IMG*W_IMG);
    const float* xp = wmed + pbase;           // x = wmed, y = cover
    const float* yp = cover + pbase;
    const int Y0  = ys << 8;                  // 0, 256
    const int tx0 = bx*TW - HALO;
    const bool xin = (bx != 0) && (bx != 15); // fast-path columns

    float ssim_acc = 0.f, mse_acc = 0.f;

    for (int k = 0; k < NCHUNK; ++k) {
        // ---- Stage A: hconv the NEW rows of this chunk into the ring ----
        // chunk 0: hr in [-5, 69) (74 rows); chunk k>0: hr in [64k+5, 64k+69)
        const int nrows = (k == 0) ? (CH + 2*HALO) : CH;
        const int hr0   = (k == 0) ? -HALO : (CH*k + HALO);
        const int ntask = nrows << 3;          // 8 col-groups of 4

        for (int t = tid; t < ntask; t += NTHREADS) {
            const int r  = t >> 3, c0 = (t & 7) << 2;
            const int hr = hr0 + r;                  // strip-relative row
            const int gy = Y0 + hr;                  // global row
            const int slot = (hr + HALO) % RING;     // ring slot (>=0)
            const bool rok = (unsigned)gy < (unsigned)H_IMG;
            float xv[14], yv[14];
            if (rok) {
                // ga = bx*32 + c0 - 8 : float4-aligned, in [-8, 500]
                const int ga = tx0 + c0 - 3;
                const float* rx = xp + (size_t)gy*W_IMG + ga;
                const float* ry = yp + (size_t)gy*W_IMG + ga;
                float4 XA, XB, XC, XD, YA, YB, YC, YD;
                float  XE, YE;
                if (xin) {
                    XA = *(const float4*)(rx);
                    XB = *(const float4*)(rx + 4);
                    XC = *(const float4*)(rx + 8);
                    XD = *(const float4*)(rx + 12);
                    XE = rx[16];
                    YA = *(const float4*)(ry);
                    YB = *(const float4*)(ry + 4);
                    YC = *(const float4*)(ry + 8);
                    YD = *(const float4*)(ry + 12);
                    YE = ry[16];
                } else {
                    // Edge strip: each float4 is fully in-range or fully
                    // OOB (ga multiple of 4). Predicated vector loads.
                    const float4 z4 = make_float4(0.f, 0.f, 0.f, 0.f);
                    const bool okA = (unsigned)(ga     ) <= (unsigned)(W_IMG-4);
                    const bool okB = (unsigned)(ga +  4) <= (unsigned)(W_IMG-4);
                    const bool okC = (unsigned)(ga +  8) <= (unsigned)(W_IMG-4);
                    const bool okD = (unsigned)(ga + 12) <= (unsigned)(W_IMG-4);
                    const bool okE = (unsigned)(ga + 16) <= (unsigned)(W_IMG-1);
                    XA = okA ? *(const float4*)(rx)      : z4;
                    XB = okB ? *(const float4*)(rx + 4)  : z4;
                    XC = okC ? *(const float4*)(rx + 8)  : z4;
                    XD = okD ? *(const float4*)(rx + 12) : z4;
                    XE = okE ? rx[16] : 0.f;
                    YA = okA ? *(const float4*)(ry)      : z4;
                    YB = okB ? *(const float4*)(ry + 4)  : z4;
                    YC = okC ? *(const float4*)(ry + 8)  : z4;
                    YD = okD ? *(const float4*)(ry + 12) : z4;
                    YE = okE ? ry[16] : 0.f;
                }
                xv[0]=XA.w;  xv[1]=XB.x;  xv[2]=XB.y;  xv[3]=XB.z;  xv[4]=XB.w;
                xv[5]=XC.x;  xv[6]=XC.y;  xv[7]=XC.z;  xv[8]=XC.w;  xv[9]=XD.x;
                xv[10]=XD.y; xv[11]=XD.z; xv[12]=XD.w; xv[13]=XE;
                yv[0]=YA.w;  yv[1]=YB.x;  yv[2]=YB.y;  yv[3]=YB.z;  yv[4]=YB.w;
                yv[5]=YC.x;  yv[6]=YC.y;  yv[7]=YC.z;  yv[8]=YC.w;  yv[9]=YD.x;
                yv[10]=YD.y; yv[11]=YD.z; yv[12]=YD.w; yv[13]=YE;
            } else {
#pragma unroll
                for (int j = 0; j < 14; ++j) { xv[j] = 0.f; yv[j] = 0.f; }
            }

            const bool own = (unsigned)hr < (unsigned)STRIP;

            // Packed hconv of {s, d, s^2, d^2}: output-col pairs in f2.
            // MSE fused: d^2 at window cols j=5..8 on owned rows.
            f2 A[NF][2];
#pragma unroll
            for (int f = 0; f < NF; ++f) { A[f][0] = splat2(0.f); A[f][1] = splat2(0.f); }
#pragma unroll
            for (int j = 0; j < 14; ++j) {
                float sj = xv[j] + yv[j];
                float dj = xv[j] - yv[j];
                float s2 = sj*sj, d2 = dj*dj;
                if (j >= 5 && j < 9) {
                    if (own) mse_acc += d2;
                }
#pragma unroll
                for (int p = 0; p < 2; ++p) {
                    const int t0 = j - 2*p;          // tap for m=2p; m=2p+1 uses t0-1
                    if (t0 >= 0 && t0 <= WS11) {
                        const f2 wp = {WT(t0), WT(t0-1)};
                        A[0][p] = __builtin_elementwise_fma(wp, splat2(sj), A[0][p]);
                        A[1][p] = __builtin_elementwise_fma(wp, splat2(dj), A[1][p]);
                        A[2][p] = __builtin_elementwise_fma(wp, splat2(s2), A[2][p]);
                        A[3][p] = __builtin_elementwise_fma(wp, splat2(d2), A[3][p]);
                    }
                }
            }
            float* wb = &rbuf[slot*RS + c0];
#pragma unroll
            for (int f = 0; f < NF; ++f) {
                *(float4*)(wb + f*FSTR) =
                    make_float4(A[f][0].x, A[f][0].y, A[f][1].x, A[f][1].y);
            }
        }
        __syncthreads();

        // ---- Stage B: vertical 11-tap + SSIM; ALL 512 threads.
        //      Task = 4 output rows x 1 col; row-pair packed f2 accums,
        //      b32 LDS reads (bank-conflict-free pattern, measured 0). ----
        {
            const int c  = tid & 31;             // column
            const int rg = tid >> 5;             // row group 0..15
            const int sb = (CH*k + (rg << 2)) % RING;  // slot of row y0-5
            f2 acc[NF][2];
#pragma unroll
            for (int f = 0; f < NF; ++f) {
                acc[f][0] = splat2(0.f); acc[f][1] = splat2(0.f);
            }
            const float* bp = rbuf + c;
#pragma unroll
            for (int i = 0; i < 14; ++i) {
                int sl = sb + i; if (sl >= RING) sl -= RING;
                const float* rp = bp + sl*RS;
#pragma unroll
                for (int f = 0; f < NF; ++f) {
                    float v = rp[f*FSTR];
#pragma unroll
                    for (int p = 0; p < 2; ++p) {
                        const int t0 = i - 2*p;      // tap for row 2p; 2p+1 uses t0-1
                        if (t0 >= 0 && t0 <= WS11) {
                            const f2 wp = {WT(t0), WT(t0-1)};
                            acc[f][p] = __builtin_elementwise_fma(wp, splat2(v), acc[f][p]);
                        }
                    }
                }
            }
            const f2 c1v = {1e-4f, 1e-4f};
            const f2 c2v = {9e-4f, 9e-4f};
            const f2 half = {0.5f, 0.5f};
#pragma unroll
            for (int p = 0; p < 2; ++p) {
                f2 S = acc[0][p], D = acc[1][p];
                f2 Cs = acc[2][p], Cd = acc[3][p];
                f2 SS = S*S, DD = D*D;
                f2 mxmy2 = (SS - DD) * half;         // 2*mx*my
                f2 msq   = (SS + DD) * half;         // mx^2+my^2
                f2 sxy2  = (Cs - Cd) * half - mxmy2; // 2*sxy
                f2 ssum  = (Cs + Cd) * half - msq;   // sxx+syy
                f2 num = (mxmy2 + c1v) * (sxy2 + c2v);
                f2 den = (msq + c1v) * (ssum + c2v);
                ssim_acc += __fdividef(num.x, den.x) + __fdividef(num.y, den.y);
            }
        }
        __syncthreads();   // ring rows reused by next chunk
    }

    // ---- Block reduce (8 waves of 64); reuse rbuf as scratch ----
#pragma unroll
    for (int off = 32; off > 0; off >>= 1) {
        ssim_acc += __shfl_down(ssim_acc, off);
        mse_acc  += __shfl_down(mse_acc, off);
    }
    const int wid = tid >> 6, lane = tid & 63;
    if (lane == 0) { rbuf[wid] = ssim_acc; rbuf[8+wid] = mse_acc; }
    __syncthreads();
    if (tid == 0) {
        float s = 0.f, m = 0.f;
#pragma unroll
        for (int i = 0; i < 8; ++i) { s += rbuf[i]; m += rbuf[8+i]; }
        part[blockIdx.x] = s;
        part[nParts + blockIdx.x] = m;
    }
}

// 1024-thread finalize: vectorized partial reduce (double), fast-log BCE,
// curriculum weights.
#define FT 1024
__global__ __launch_bounds__(FT) void finalize_k(
        const float* __restrict__ part, int nParts,
        const float* __restrict__ wm_orig, const float* __restrict__ wm_ext,
        int nWm, const int* __restrict__ epoch_p,
        float* __restrict__ out, double inv_npix, double inv_nwm) {
    __shared__ double red[48];
    int tid = threadIdx.x;
    double s_ssim = 0.0, s_mse = 0.0, s_wl = 0.0;
    const float4* s4 = (const float4*)part;
    const float4* m4 = (const float4*)(part + nParts);
    int n4 = nParts >> 2;
    for (int i = tid; i < n4; i += FT) {
        float4 v = s4[i];
        s_ssim += (double)((v.x + v.y) + (v.z + v.w));
        float4 u = m4[i];
        s_mse  += (double)((u.x + u.y) + (u.z + u.w));
    }
    const float4* p4 = (const float4*)wm_orig;
    const float4* q4 = (const float4*)wm_ext;
    int w4 = nWm >> 2;
    for (int i = tid; i < w4; i += FT) {
        float4 p = p4[i], q = q4[i];
        float a;
        a  = -(p.x*__logf(q.x) + (1.f-p.x)*__logf(1.f-q.x));
        a += -(p.y*__logf(q.y) + (1.f-p.y)*__logf(1.f-q.y));
        a += -(p.z*__logf(q.z) + (1.f-p.z)*__logf(1.f-q.z));
        a += -(p.w*__logf(q.w) + (1.f-p.w)*__logf(1.f-q.w));
        s_wl += (double)a;
    }
#pragma unroll
    for (int off = 32; off > 0; off >>= 1) {
        s_ssim += __shfl_down(s_ssim, off);
        s_mse  += __shfl_down(s_mse, off);
        s_wl   += __shfl_down(s_wl, off);
    }
    int wid = tid >> 6, lane = tid & 63;
    if (lane == 0) { red[wid] = s_ssim; red[16+wid] = s_mse; red[32+wid] = s_wl; }
    __syncthreads();
    if (tid == 0) {
        double ssim_sum = 0.0, mse_sum = 0.0, wl_sum = 0.0;
        for (int i = 0; i < 16; ++i) {
            ssim_sum += red[i]; mse_sum += red[16+i]; wl_sum += red[32+i];
        }
        float sv = (float)(ssim_sum * inv_npix);
        float ml = (float)(mse_sum  * inv_npix);
        float wl = (float)(wl_sum   * inv_nwm);
        int e = *epoch_p;
        float w_img, w_ssim;
        if (e <= 12) {
            w_img = 0.05f; w_ssim = 0.05f;
        } else {
            float progress = fminf(1.0f, (float)(e - 12) / 10.0f);
            w_img  = 0.05f + (0.5f - 0.05f)*progress;
            w_ssim = 0.05f + (0.8f - 0.05f)*progress;
        }
        float sl = 1.0f - sv;
        float total = w_img*ml + w_ssim*sl + 3.0f*wl;
        out[0] = total;
        out[1] = ml;
        out[2] = sv;
        out[3] = wl;
    }
}

extern "C" void kernel_launch(void* const* d_in, const int* in_sizes, int n_in,
                              void* d_out, int out_size, void* d_ws, size_t ws_size,
                              hipStream_t stream) {
    const float* cover   = (const float*)d_in[0];
    const float* wmed    = (const float*)d_in[1];
    const float* wm_orig = (const float*)d_in[2];
    const float* wm_ext  = (const float*)d_in[3];
    const int*   epoch   = (const int*)d_in[4];
    float* out = (float*)d_out;

    int npix   = in_sizes[0];                 // 12,582,912
    int planes = npix / (H_IMG * W_IMG);      // 48
    int nWm    = in_sizes[2];                 // 16,384

    int nBlocks = 16 * 2 * planes;            // 1536 column-strip blocks
    int nParts  = nBlocks;
    float* part = (float*)d_ws;               // 2 * nParts floats (12 KB)

    ssim_mse_tile<<<nBlocks, NTHREADS, 0, stream>>>(cover, wmed, part, nParts);
    finalize_k<<<1, FT, 0, stream>>>(part, nParts, wm_orig, wm_ext, nWm,
                                     epoch, out,
                                     1.0 / (double)npix, 1.0 / (double)nWm);
}